// Round 4
// baseline (963.744 us; speedup 1.0000x reference)
//
#include <hip/hip_runtime.h>

// Problem constants (fixed by setup_inputs)
#define BB 4
#define HH 256
#define WW 512
#define LL 21
#define NEL (BB*HH*WW*LL)   // 11,010,048 elements per field
#define NDIR 4
#define PD 4                // global->reg prefetch distance (steps)

// ---------------------------------------------------------------------------
// Elementwise: out = phi*scale + msgs[0] + msgs[1] + msgs[2] + msgs[3]
// scale=1 -> "total" for next sweep; scale=2 -> final unary belief.
// ---------------------------------------------------------------------------
__global__ __launch_bounds__(256) void ewise_kernel(
    const float* __restrict__ phi, const float* __restrict__ msgs,
    float* __restrict__ out, float scale)
{
    int i = blockIdx.x * 256 + threadIdx.x;
    const float4* p4 = (const float4*)phi;
    const float4* m0 = (const float4*)(msgs + 0 * NEL);
    const float4* m1 = (const float4*)(msgs + 1 * NEL);
    const float4* m2 = (const float4*)(msgs + 2 * NEL);
    const float4* m3 = (const float4*)(msgs + 3 * NEL);
    float4 a = p4[i];
    float4 b0 = m0[i], b1 = m1[i], b2 = m2[i], b3 = m3[i];
    float4 r;
    r.x = a.x * scale + b0.x + b1.x + b2.x + b3.x;
    r.y = a.y * scale + b0.y + b1.y + b2.y + b3.y;
    r.z = a.z * scale + b0.z + b1.z + b2.z + b3.z;
    r.w = a.w * scale + b0.w + b1.w + b2.w + b3.w;
    ((float4*)out)[i] = r;
}

// ---------------------------------------------------------------------------
// 8-lane-group min (broadcast to all 8 lanes), pure DPP — no DS pipe.
// quad_perm xor1 (0xB1), quad_perm xor2 (0x4E), row_half_mirror (0x141).
// ---------------------------------------------------------------------------
__device__ __forceinline__ float min8(float x)
{
    int xi = __float_as_int(x);
    int y;
    y  = __builtin_amdgcn_update_dpp(xi, xi, 0xB1, 0xf, 0xf, false);
    x  = fminf(x, __int_as_float(y)); xi = __float_as_int(x);
    y  = __builtin_amdgcn_update_dpp(xi, xi, 0x4E, 0xf, 0xf, false);
    x  = fminf(x, __int_as_float(y)); xi = __float_as_int(x);
    y  = __builtin_amdgcn_update_dpp(xi, xi, 0x141, 0xf, 0xf, false);
    x  = fminf(x, __int_as_float(y));
    return x;
}

// ---------------------------------------------------------------------------
// Directional sweep, all 4 directions in one launch.
// 8 lanes per scanline: lane k of a group owns labels {k, k+8, k+16}
// (labels 21..23 are dummies held at 1e30). One wave (64 thr) = 8 lines,
// one block = one wave, 768 blocks = 6144 lines -> 3 waves/CU, balanced
// ~1 horizontal + 2 vertical per CU.
//
// Potts fast path (unnormalized, exact):
//   T_0 = u_0;  Tmin_s = min_l T_s(l);  Q_s = Tmin_s + c
//   T_{s+1}(l) = u_{s+1}(l) + min(T_s(l), Q_s)
//   m_{s+1}(l) = min(T_s(l), Q_s) - Tmin_s          (m_0 = 0)
// In-place msgs: reads lead writes by PD steps on the same line.
// ---------------------------------------------------------------------------
template<bool FIRST>
__global__ __launch_bounds__(64) void sweep_kernel(
    const float* __restrict__ tot, const float* __restrict__ ctx,
    float* __restrict__ msgs)
{
    __shared__ float shc[LL * LL];   // general path only
    __shared__ float shrm[LL];
    __shared__ float sht[8][24];

    const int lane = threadIdx.x;
    const int g = lane >> 3, k = lane & 7;
    const int line = blockIdx.x * 8 + g;

    int d, S, stride, base;
    if (line < 2048) {                    // horizontal
        d = line >> 10;                   // 0 or 1
        int r = line & 1023;              // b*H + h  (B*H = 1024)
        S = WW; base = r * (WW * LL); stride = LL;
        if (d == 1) { base += (WW - 1) * LL; stride = -LL; }
    } else {                              // vertical
        int v = line - 2048;
        d = 2 + (v >> 11);                // 2 or 3
        int r = v & 2047;
        int bb = r >> 9, w = r & 511;
        S = HH; base = (bb * HH * WW + w) * LL; stride = WW * LL;
        if (d == 3) { base += (HH - 1) * WW * LL; stride = -stride; }
    }

    const float* ctxd = ctx + d * (LL * LL);
    const float  c    = ctxd[1];          // candidate Potts constant

    // Runtime Potts detection: lane checks its own label columns.
    bool bad = (c < 0.f);
    #pragma unroll
    for (int t = 0; t < 3; ++t) {
        int j = k + 8 * t;
        if (j < LL) {
            for (int l = 0; l < LL; ++l) {
                float want = (l == j) ? 0.f : c;
                if (ctxd[l * LL + j] != want) bad = true;
            }
        }
    }
    const bool potts = (__ballot(bad) == 0ull);

    const bool act2  = (k < 5);           // label k+16 < 21
    const int  j2rel = act2 ? 16 : 0;     // clamped (in-bounds, value dummied)

    const float* tp0   = tot  + base + k;
    float*       mbase = msgs + (size_t)d * NEL + base + k;

    // register prefetch FIFO, depth PD=4, 3 slots each for tot and msg_old
    float a[4], b[4], cc[4], fa[4], fb[4], fc[4];
    #pragma unroll
    for (int i = 0; i < 4; ++i) {
        int off = i * stride;
        a[i]  = tp0[off];
        b[i]  = tp0[off + 8];
        cc[i] = tp0[off + j2rel];
        fa[i] = FIRST ? 0.f : mbase[off];
        fb[i] = FIRST ? 0.f : mbase[off + 8];
        fc[i] = FIRST ? 0.f : mbase[off + j2rel];
    }
    const float* tld = tp0   + PD * stride;
    const float* mld = mbase + PD * stride;
    float*       mst = mbase;

    if (potts) {
        float mn0 = 0.f, mn1 = 0.f, mn2 = 0.f, tminp = 0.f;  // -> m_0 = 0

        auto step = [&](float tA, float tB, float tC,
                        float fA, float fB, float fC) {
            mst[0] = mn0 - tminp;
            mst[8] = mn1 - tminp;
            if (act2) mst[16] = mn2 - tminp;
            mst += stride;
            float u0 = tA - fA, u1 = tB - fB;
            float u2 = act2 ? (tC - fC) : 1e30f;
            float T0 = u0 + mn0, T1 = u1 + mn1, T2 = u2 + mn2;
            float lm = fminf(fminf(T0, T1), T2);
            lm = min8(lm);
            float Q = lm + c;
            mn0 = fminf(T0, Q); mn1 = fminf(T1, Q); mn2 = fminf(T2, Q);
            tminp = lm;
        };

        for (int s = 0; s < S - PD; s += 4) {
            #pragma unroll
            for (int i = 0; i < 4; ++i) {
                float tA = a[i], tB = b[i], tC = cc[i];
                float fA = fa[i], fB = fb[i], fC = fc[i];
                a[i]  = tld[0];
                b[i]  = tld[8];
                cc[i] = tld[j2rel];
                if (!FIRST) {
                    fa[i] = mld[0];
                    fb[i] = mld[8];
                    fc[i] = mld[j2rel];
                }
                tld += stride; mld += stride;
                step(tA, tB, tC, fA, fB, fC);
            }
        }
        #pragma unroll
        for (int i = 0; i < 4; ++i)
            step(a[i], b[i], cc[i], fa[i], fb[i], fc[i]);
    } else {
        // -------- general min-plus path (correct for arbitrary ctx; not
        // taken on the bench input). ctx + rowmin staged in LDS. --------
        for (int i = lane; i < LL * LL; i += 64) shc[i] = ctxd[i];
        __syncthreads();
        if (lane < LL) {
            float mn = shc[lane * LL];
            for (int j = 1; j < LL; ++j) mn = fminf(mn, shc[lane * LL + j]);
            shrm[lane] = mn;
        }
        __syncthreads();

        float m0 = 0.f, m1 = 0.f, m2 = 0.f;
        auto gstep = [&](float tA, float tB, float tC,
                         float fA, float fB, float fC) {
            mst[0] = m0;
            mst[8] = m1;
            if (act2) mst[16] = m2;
            mst += stride;
            float t0 = tA - fA + m0, t1 = tB - fB + m1;
            float t2 = act2 ? (tC - fC + m2) : 1e30f;
            __syncthreads();                 // prev reads done before rewrite
            sht[g][k] = t0; sht[g][k + 8] = t1;
            if (act2) sht[g][k + 16] = t2;
            __syncthreads();
            float mnA = 1e30f, mnB = 1e30f, mnC = 1e30f, gm = 1e30f;
            for (int l = 0; l < LL; ++l) {
                float tl = sht[g][l];
                mnA = fminf(mnA, tl + shc[l * LL + k]);
                mnB = fminf(mnB, tl + shc[l * LL + k + 8]);
                if (act2) mnC = fminf(mnC, tl + shc[l * LL + k + 16]);
                gm  = fminf(gm,  tl + shrm[l]);
            }
            m0 = mnA - gm; m1 = mnB - gm; m2 = mnC - gm;
        };

        for (int s = 0; s < S - PD; s += 4) {
            #pragma unroll
            for (int i = 0; i < 4; ++i) {
                float tA = a[i], tB = b[i], tC = cc[i];
                float fA = fa[i], fB = fb[i], fC = fc[i];
                a[i]  = tld[0];
                b[i]  = tld[8];
                cc[i] = tld[j2rel];
                if (!FIRST) {
                    fa[i] = mld[0];
                    fb[i] = mld[8];
                    fc[i] = mld[j2rel];
                }
                tld += stride; mld += stride;
                gstep(tA, tB, tC, fA, fB, fC);
            }
        }
        #pragma unroll
        for (int i = 0; i < 4; ++i)
            gstep(a[i], b[i], cc[i], fa[i], fb[i], fc[i]);
    }
}

// ---------------------------------------------------------------------------
extern "C" void kernel_launch(void* const* d_in, const int* in_sizes, int n_in,
                              void* d_out, int out_size, void* d_ws, size_t ws_size,
                              hipStream_t stream)
{
    (void)in_sizes; (void)n_in; (void)out_size; (void)ws_size;

    const float* phi = (const float*)d_in[0];
    const float* ctx = (const float*)d_in[1];   // [4,21,21]
    float* out  = (float*)d_out;                // doubles as "total" scratch
    float* msgs = (float*)d_ws;                 // 4 * NEL floats, in-place

    const int EW_BLOCKS = NEL / 4 / 256;        // 10752, exact
    const int SW_BLOCKS = 6144 / 8;             // 768 one-wave blocks

    // iteration 1: total == phi, old msgs == 0 (never read -> poison-safe)
    sweep_kernel<true><<<SW_BLOCKS, 64, 0, stream>>>(phi, ctx, msgs);

    for (int it = 1; it < 5; ++it) {
        ewise_kernel<<<EW_BLOCKS, 256, 0, stream>>>(phi, msgs, out, 1.0f);
        sweep_kernel<false><<<SW_BLOCKS, 64, 0, stream>>>(out, ctx, msgs);
    }

    // final belief: phi*GAMMA_MNODE + sum of messages
    ewise_kernel<<<EW_BLOCKS, 256, 0, stream>>>(phi, msgs, out, 2.0f);
}

// Round 5
// 773.847 us; speedup vs baseline: 1.2454x; 1.2454x over previous
//
#include <hip/hip_runtime.h>

// Problem constants (fixed by setup_inputs)
#define BB 4
#define HH 256
#define WW 512
#define LL 21
#define NEL (BB*HH*WW*LL)   // 11,010,048 elements per field
#define NDIR 4
#define PD 16               // global->reg prefetch distance (steps); divides 496 & 240

// ---------------------------------------------------------------------------
// Elementwise: out = phi*scale + msgs[0] + msgs[1] + msgs[2] + msgs[3]
// ---------------------------------------------------------------------------
__global__ __launch_bounds__(256) void ewise_kernel(
    const float* __restrict__ phi, const float* __restrict__ msgs,
    float* __restrict__ out, float scale)
{
    int i = blockIdx.x * 256 + threadIdx.x;
    const float4* p4 = (const float4*)phi;
    const float4* m0 = (const float4*)(msgs + 0 * NEL);
    const float4* m1 = (const float4*)(msgs + 1 * NEL);
    const float4* m2 = (const float4*)(msgs + 2 * NEL);
    const float4* m3 = (const float4*)(msgs + 3 * NEL);
    float4 a = p4[i];
    float4 b0 = m0[i], b1 = m1[i], b2 = m2[i], b3 = m3[i];
    float4 r;
    r.x = a.x * scale + b0.x + b1.x + b2.x + b3.x;
    r.y = a.y * scale + b0.y + b1.y + b2.y + b3.y;
    r.z = a.z * scale + b0.z + b1.z + b2.z + b3.z;
    r.w = a.w * scale + b0.w + b1.w + b2.w + b3.w;
    ((float4*)out)[i] = r;
}

// ---------------------------------------------------------------------------
// 8-lane-group min (broadcast to all 8 lanes), pure DPP — no DS pipe.
// ---------------------------------------------------------------------------
__device__ __forceinline__ float min8(float x)
{
    int xi = __float_as_int(x);
    int y;
    y  = __builtin_amdgcn_update_dpp(xi, xi, 0xB1, 0xf, 0xf, false);  // xor1
    x  = fminf(x, __int_as_float(y)); xi = __float_as_int(x);
    y  = __builtin_amdgcn_update_dpp(xi, xi, 0x4E, 0xf, 0xf, false);  // xor2
    x  = fminf(x, __int_as_float(y)); xi = __float_as_int(x);
    y  = __builtin_amdgcn_update_dpp(xi, xi, 0x141, 0xf, 0xf, false); // half-mirror
    x  = fminf(x, __int_as_float(y));
    return x;
}

// ---------------------------------------------------------------------------
// Directional sweep, all 4 directions in one launch.
// 8 lanes per scanline; lane k (k<7) owns labels {3k,3k+1,3k+2} via one
// float3 load/store; lane 7 is a dummy (loads offset 0, min forced 1e30,
// store masked). 8 lines/wave, 1 wave/block, 768 blocks = 3 waves/CU.
//
// Potts fast path (unnormalized, exact):
//   T_0 = u_0;  Tmin_s = min_l T_s(l);  Q_s = Tmin_s + c
//   T_{s+1}(l) = u_{s+1}(l) + min(T_s(l), Q_s)
//   m_{s+1}(l) = min(T_s(l), Q_s) - Tmin_s          (m_0 = 0)
// In-place msgs: position p is read (prefetch) at step p-PD, written at p.
// ---------------------------------------------------------------------------
template<bool FIRST>
__global__ __launch_bounds__(64) void sweep_kernel(
    const float* __restrict__ tot, const float* __restrict__ ctx,
    float* __restrict__ msgs)
{
    __shared__ float shc[LL * LL];   // general (non-Potts) path only
    __shared__ float shrm[LL];
    __shared__ float sht[8][24];

    const int lane = threadIdx.x;
    const int g = lane >> 3, k = lane & 7;
    const int line = blockIdx.x * 8 + g;

    int d, S, stride, base;
    if (line < 2048) {                    // horizontal
        d = line >> 10;                   // 0 or 1
        int r = line & 1023;              // b*H + h  (B*H = 1024)
        S = WW; base = r * (WW * LL); stride = LL;
        if (d == 1) { base += (WW - 1) * LL; stride = -LL; }
    } else {                              // vertical
        int v = line - 2048;
        d = 2 + (v >> 11);                // 2 or 3
        int r = v & 2047;
        int bb = r >> 9, w = r & 511;
        S = HH; base = (bb * HH * WW + w) * LL; stride = WW * LL;
        if (d == 3) { base += (HH - 1) * WW * LL; stride = -stride; }
    }

    const float* ctxd = ctx + d * (LL * LL);
    const float  c    = ctxd[1];          // candidate Potts constant

    // Runtime Potts detection: lane k<7 checks its three columns.
    bool bad = (c < 0.f);
    if (k < 7) {
        #pragma unroll
        for (int t = 0; t < 3; ++t) {
            int j = 3 * k + t;
            for (int l = 0; l < LL; ++l) {
                float want = (l == j) ? 0.f : c;
                if (ctxd[l * LL + j] != want) bad = true;
            }
        }
    }
    const bool potts = (__ballot(bad) == 0ull);

    const bool act = (k < 7);
    const int  off = act ? 3 * k : 0;     // lane 7: safe dummy address

    const float* tp = tot  + base + off;
    float*       mp = msgs + (size_t)d * NEL + base + off;

    // register prefetch FIFO, depth PD, float3 slots
    float3 ta[PD], fa[PD];
    #pragma unroll
    for (int i = 0; i < PD; ++i) {
        ta[i] = *(const float3*)(tp + i * stride);
        if (FIRST) fa[i] = make_float3(0.f, 0.f, 0.f);
        else       fa[i] = *(const float3*)(mp + i * stride);
    }
    const float* tld = tp + PD * stride;
    const float* mld = mp + PD * stride;
    float*       mst = mp;

    if (potts) {
        float mn0 = 0.f, mn1 = 0.f, mn2 = 0.f, tminp = 0.f;   // -> m_0 = 0

        auto step = [&](const float3& tc, const float3& fo) {
            if (act) {
                float3 msg;
                msg.x = mn0 - tminp; msg.y = mn1 - tminp; msg.z = mn2 - tminp;
                *(float3*)mst = msg;
            }
            mst += stride;
            float T0 = (tc.x - fo.x) + mn0;
            float T1 = (tc.y - fo.y) + mn1;
            float T2 = (tc.z - fo.z) + mn2;
            float lm = fminf(fminf(T0, T1), T2);
            lm = act ? lm : 1e30f;
            lm = min8(lm);
            float Q = lm + c;
            mn0 = fminf(T0, Q); mn1 = fminf(T1, Q); mn2 = fminf(T2, Q);
            tminp = lm;
        };

        const int outer = (S - PD) / PD;
        for (int o = 0; o < outer; ++o) {
            #pragma unroll
            for (int i = 0; i < PD; ++i) {
                float3 tc = ta[i], fo = fa[i];
                ta[i] = *(const float3*)tld;
                if (!FIRST) fa[i] = *(const float3*)mld;
                tld += stride; mld += stride;
                step(tc, fo);
            }
        }
        #pragma unroll
        for (int i = 0; i < PD; ++i) step(ta[i], fa[i]);
    } else {
        // -------- general min-plus path (correct for arbitrary ctx; not
        // taken on the bench input). ctx + rowmin staged in LDS. --------
        for (int i = lane; i < LL * LL; i += 64) shc[i] = ctxd[i];
        __syncthreads();
        if (lane < LL) {
            float mn = shc[lane * LL];
            for (int j = 1; j < LL; ++j) mn = fminf(mn, shc[lane * LL + j]);
            shrm[lane] = mn;
        }
        __syncthreads();

        float m0 = 0.f, m1 = 0.f, m2 = 0.f;
        auto gstep = [&](const float3& tc, const float3& fo) {
            if (act) {
                float3 msg; msg.x = m0; msg.y = m1; msg.z = m2;
                *(float3*)mst = msg;
            }
            mst += stride;
            float t0 = (tc.x - fo.x) + m0;
            float t1 = (tc.y - fo.y) + m1;
            float t2 = (tc.z - fo.z) + m2;
            __syncthreads();                 // prior reads done before rewrite
            if (act) {
                sht[g][3 * k]     = t0;
                sht[g][3 * k + 1] = t1;
                sht[g][3 * k + 2] = t2;
            }
            __syncthreads();
            float mnA = 1e30f, mnB = 1e30f, mnC = 1e30f, gm = 1e30f;
            for (int l = 0; l < LL; ++l) {
                float tl = sht[g][l];
                if (act) {
                    mnA = fminf(mnA, tl + shc[l * LL + 3 * k]);
                    mnB = fminf(mnB, tl + shc[l * LL + 3 * k + 1]);
                    mnC = fminf(mnC, tl + shc[l * LL + 3 * k + 2]);
                }
                gm = fminf(gm, tl + shrm[l]);
            }
            m0 = mnA - gm; m1 = mnB - gm; m2 = mnC - gm;
        };

        const int outer = (S - PD) / PD;
        for (int o = 0; o < outer; ++o) {
            #pragma unroll
            for (int i = 0; i < PD; ++i) {
                float3 tc = ta[i], fo = fa[i];
                ta[i] = *(const float3*)tld;
                if (!FIRST) fa[i] = *(const float3*)mld;
                tld += stride; mld += stride;
                gstep(tc, fo);
            }
        }
        #pragma unroll
        for (int i = 0; i < PD; ++i) gstep(ta[i], fa[i]);
    }
}

// ---------------------------------------------------------------------------
extern "C" void kernel_launch(void* const* d_in, const int* in_sizes, int n_in,
                              void* d_out, int out_size, void* d_ws, size_t ws_size,
                              hipStream_t stream)
{
    (void)in_sizes; (void)n_in; (void)out_size; (void)ws_size;

    const float* phi = (const float*)d_in[0];
    const float* ctx = (const float*)d_in[1];   // [4,21,21]
    float* out  = (float*)d_out;                // doubles as "total" scratch
    float* msgs = (float*)d_ws;                 // 4 * NEL floats, in-place

    const int EW_BLOCKS = NEL / 4 / 256;        // 10752, exact
    const int SW_BLOCKS = 6144 / 8;             // 768 one-wave blocks

    // iteration 1: total == phi, old msgs == 0 (never read -> poison-safe)
    sweep_kernel<true><<<SW_BLOCKS, 64, 0, stream>>>(phi, ctx, msgs);

    for (int it = 1; it < 5; ++it) {
        ewise_kernel<<<EW_BLOCKS, 256, 0, stream>>>(phi, msgs, out, 1.0f);
        sweep_kernel<false><<<SW_BLOCKS, 64, 0, stream>>>(out, ctx, msgs);
    }

    // final belief: phi*GAMMA_MNODE + sum of messages
    ewise_kernel<<<EW_BLOCKS, 256, 0, stream>>>(phi, msgs, out, 2.0f);
}

// Round 7
// 682.203 us; speedup vs baseline: 1.4127x; 1.1343x over previous
//
#include <hip/hip_runtime.h>

// Problem constants (fixed by setup_inputs)
#define BB 4
#define HH 256
#define WW 512
#define LL 21
#define PIX (BB*HH*WW)        // 524288 pixels
#define NEL (PIX*LL)          // 11,010,048 floats per packed fp32 field
#define MSL 24                // padded fp16 labels per pixel (48 B)
#define TSL 24                // padded fp32 labels per pixel (96 B)
#define MFLD ((size_t)PIX*MSL)// elements per direction's fp16 msg field
#define PD 16                 // prefetch distance; divides 496 and 240

typedef float    fvec4 __attribute__((ext_vector_type(4)));
typedef _Float16 hvec4 __attribute__((ext_vector_type(4)));
typedef _Float16 hvec8 __attribute__((ext_vector_type(8)));

// Unaligned (4-B) vector access helpers — defined behavior, emit dwordx4.
__device__ __forceinline__ fvec4 load4u(const float* p) {
    fvec4 v; __builtin_memcpy(&v, p, 16); return v;
}
__device__ __forceinline__ void store4u(float* p, fvec4 v) {
    __builtin_memcpy(p, &v, 16);
}

// ---------------------------------------------------------------------------
// Elementwise: r(p,l) = phi*scale + sum_d msg_d.  padded_out=1 -> write
// padded-24 fp32 tot scratch (aligned); 0 -> write packed-21 fp32 (d_out).
// ---------------------------------------------------------------------------
__global__ __launch_bounds__(256) void ewise_kernel(
    const float* __restrict__ phi, const _Float16* __restrict__ msgs,
    float* __restrict__ out, float scale, int padded_out)
{
    int p = blockIdx.x * 256 + threadIdx.x;      // < PIX
    const float* pp = phi + (size_t)p * LL;

    float r[24];
    {   // phi*scale
        fvec4 u0 = load4u(pp + 0), u1 = load4u(pp + 4), u2 = load4u(pp + 8);
        fvec4 u3 = load4u(pp + 12), u4 = load4u(pp + 16);
        #pragma unroll
        for (int e = 0; e < 4; ++e) {
            r[e]      = u0[e] * scale;
            r[4 + e]  = u1[e] * scale;
            r[8 + e]  = u2[e] * scale;
            r[12 + e] = u3[e] * scale;
            r[16 + e] = u4[e] * scale;
        }
        r[20] = pp[20] * scale;
        r[21] = r[22] = r[23] = 0.f;
    }

    #pragma unroll
    for (int d = 0; d < 4; ++d) {
        const _Float16* mp = msgs + (size_t)d * MFLD + (size_t)p * MSL;
        hvec8 h0 = *(const hvec8*)(mp + 0);      // 16-B aligned (48-B rows)
        hvec8 h1 = *(const hvec8*)(mp + 8);
        hvec8 h2 = *(const hvec8*)(mp + 16);
        #pragma unroll
        for (int e = 0; e < 8; ++e) r[e]      += (float)h0[e];
        #pragma unroll
        for (int e = 0; e < 8; ++e) r[8 + e]  += (float)h1[e];
        #pragma unroll
        for (int e = 0; e < 5; ++e) r[16 + e] += (float)h2[e];
    }

    if (padded_out) {
        float* op = out + (size_t)p * TSL;       // 96-B rows, 16-B aligned
        r[21] = r[22] = r[23] = 0.f;             // pads (sweep sanitizes anyway)
        #pragma unroll
        for (int e = 0; e < 6; ++e)
            *(fvec4*)(op + 4 * e) = *(const fvec4*)(r + 4 * e);
    } else {
        float* op = out + (size_t)p * LL;        // packed final output
        store4u(op + 0,  *(const fvec4*)(r + 0));
        store4u(op + 4,  *(const fvec4*)(r + 4));
        store4u(op + 8,  *(const fvec4*)(r + 8));
        store4u(op + 12, *(const fvec4*)(r + 12));
        store4u(op + 16, *(const fvec4*)(r + 16));
        op[20] = r[20];
    }
}

// ---------------------------------------------------------------------------
// 8-lane-group min (broadcast to all 8 lanes), pure DPP — no DS pipe.
// ---------------------------------------------------------------------------
__device__ __forceinline__ float min8(float x)
{
    int xi = __float_as_int(x);
    int y;
    y  = __builtin_amdgcn_update_dpp(xi, xi, 0xB1, 0xf, 0xf, false);  // xor1
    x  = fminf(x, __int_as_float(y)); xi = __float_as_int(x);
    y  = __builtin_amdgcn_update_dpp(xi, xi, 0x4E, 0xf, 0xf, false);  // xor2
    x  = fminf(x, __int_as_float(y)); xi = __float_as_int(x);
    y  = __builtin_amdgcn_update_dpp(xi, xi, 0x141, 0xf, 0xf, false); // half-mirror
    x  = fminf(x, __int_as_float(y));
    return x;
}

// ---------------------------------------------------------------------------
// Directional sweep, all 4 directions in one launch.
// 8 lanes/scanline; lane k<6 owns labels {4k..4k+3}; lanes 6,7 dummy.
// FIRST: tot = packed-21 phi. Lane 5's load is clamped to element 17
//   (reads 17..20, in-bounds) and its label-20 value taken from comp 3;
//   comps for labels 21..23 are killed by the okB sanitize.
// !FIRST: tot = padded-24 fp32 scratch (aligned, in-bounds).
// msgs: fp16 padded-24, one hvec4 (8 B) per lane. In-place: position p is
// read (prefetch) at step p-PD, written at step p — same-lane order.
//
// Potts fast path (unnormalized, exact):
//   Tmin_s = min_l T_s(l);  Q_s = Tmin_s + c
//   T_{s+1}(l) = u_{s+1}(l) + min(T_s(l), Q_s)
//   m_{s+1}(l) = min(T_s(l), Q_s) - Tmin_s          (m_0 = 0)
// ---------------------------------------------------------------------------
template<bool FIRST>
__global__ __launch_bounds__(64) void sweep_kernel(
    const float* __restrict__ tot, const float* __restrict__ ctx,
    _Float16* __restrict__ msgs)
{
    __shared__ float shc[LL * LL];   // general (non-Potts) path only
    __shared__ float shrm[LL];
    __shared__ float sht[8][MSL];

    const int lane = threadIdx.x;
    const int g = lane >> 3, k = lane & 7;
    const int line = blockIdx.x * 8 + g;
    const int tsl = FIRST ? LL : TSL;

    int d, S, tstr, mstr;
    size_t tbase, mbase;
    if (line < 2048) {                    // horizontal
        d = line >> 10;                   // 0 or 1
        int r = line & 1023;              // b*H + h  (B*H = 1024)
        S = WW;
        tbase = (size_t)r * WW * tsl;
        mbase = (size_t)r * WW * MSL;
        tstr = tsl; mstr = MSL;
        if (d == 1) {
            tbase += (size_t)(WW - 1) * tsl;
            mbase += (size_t)(WW - 1) * MSL;
            tstr = -tstr; mstr = -mstr;
        }
    } else {                              // vertical
        int v = line - 2048;
        d = 2 + (v >> 11);                // 2 or 3
        int r = v & 2047;
        int bb = r >> 9, w = r & 511;
        S = HH;
        tbase = ((size_t)bb * HH * WW + w) * tsl;
        mbase = ((size_t)bb * HH * WW + w) * MSL;
        tstr = WW * tsl; mstr = WW * MSL;
        if (d == 3) {
            tbase += (size_t)(HH - 1) * WW * tsl;
            mbase += (size_t)(HH - 1) * WW * MSL;
            tstr = -tstr; mstr = -mstr;
        }
    }

    const float* ctxd = ctx + d * (LL * LL);
    const float  c    = ctxd[1];          // candidate Potts constant

    // Runtime Potts detection: lane checks its own columns 4k..4k+3.
    bool bad = (c < 0.f);
    #pragma unroll
    for (int e = 0; e < 4; ++e) {
        int j = 4 * k + e;
        if (j < LL) {
            for (int l = 0; l < LL; ++l) {
                float want = (l == j) ? 0.f : c;
                if (ctxd[l * LL + j] != want) bad = true;
            }
        }
    }
    const bool potts = (__ballot(bad) == 0ull);

    const bool act = (k < 6);
    const bool okA = (k < 6);             // component 0 valid
    const bool okB = (k < 5);             // components 1..3 valid
    // FIRST(packed): clamp lane 5 to elem 17 (in-bounds); label 20 = comp 3.
    const int koff = act ? (FIRST ? (k == 5 ? 17 : 4 * k) : 4 * k) : 0;
    const bool swap05 = FIRST && (k == 5);

    const float*  tp = tot  + tbase + koff;
    _Float16*     mp = msgs + (size_t)d * MFLD + mbase + (act ? 4 * k : 0);

    // register prefetch FIFO
    fvec4 tf[PD]; hvec4 mf[PD];
    #pragma unroll
    for (int i = 0; i < PD; ++i) {
        tf[i] = load4u(tp + (ptrdiff_t)i * tstr);
        if (FIRST) {
            hvec4 z; z[0] = z[1] = z[2] = z[3] = (_Float16)0.f;
            mf[i] = z;
        } else {
            mf[i] = *(const hvec4*)(mp + (ptrdiff_t)i * mstr);
        }
    }
    const float*    tld = tp + (ptrdiff_t)PD * tstr;
    const _Float16* mld = mp + (ptrdiff_t)PD * mstr;
    _Float16*       mst = mp;

    if (potts) {
        float mn0 = 0.f, mn1 = 0.f, mn2 = 0.f, mn3 = 0.f, tminp = 0.f;

        auto step = [&](fvec4 tc, hvec4 mo) {
            if (act) {
                hvec4 o;
                o[0] = (_Float16)(mn0 - tminp);
                o[1] = (_Float16)(mn1 - tminp);
                o[2] = (_Float16)(mn2 - tminp);
                o[3] = (_Float16)(mn3 - tminp);
                *(hvec4*)mst = o;
            }
            mst += mstr;
            float e0 = swap05 ? tc[3] : tc[0];
            float T0 = (e0    - (float)mo[0]) + mn0;
            float T1 = (tc[1] - (float)mo[1]) + mn1;
            float T2 = (tc[2] - (float)mo[2]) + mn2;
            float T3 = (tc[3] - (float)mo[3]) + mn3;
            T0 = okA ? T0 : 1e30f;        // sanitize pads/dummies
            T1 = okB ? T1 : 1e30f;
            T2 = okB ? T2 : 1e30f;
            T3 = okB ? T3 : 1e30f;
            float lm = fminf(fminf(T0, T1), fminf(T2, T3));
            lm = min8(lm);
            float Q = lm + c;
            mn0 = fminf(T0, Q); mn1 = fminf(T1, Q);
            mn2 = fminf(T2, Q); mn3 = fminf(T3, Q);
            tminp = lm;
        };

        const int outer = (S - PD) / PD;
        for (int o = 0; o < outer; ++o) {
            #pragma unroll
            for (int i = 0; i < PD; ++i) {
                fvec4 tc = tf[i]; hvec4 mo = mf[i];
                tf[i] = load4u(tld);
                if (!FIRST) mf[i] = *(const hvec4*)mld;
                tld += tstr; mld += mstr;
                step(tc, mo);
            }
        }
        #pragma unroll
        for (int i = 0; i < PD; ++i) step(tf[i], mf[i]);
    } else {
        // -------- general min-plus path (correct for arbitrary ctx; not
        // taken on the bench input). ctx + rowmin staged in LDS. --------
        for (int i = lane; i < LL * LL; i += 64) shc[i] = ctxd[i];
        __syncthreads();
        if (lane < LL) {
            float mn = shc[lane * LL];
            for (int j = 1; j < LL; ++j) mn = fminf(mn, shc[lane * LL + j]);
            shrm[lane] = mn;
        }
        __syncthreads();

        float m0 = 0.f, m1 = 0.f, m2 = 0.f, m3 = 0.f;
        const int j0 = (4 * k     < LL) ? 4 * k     : LL - 1;
        const int j1 = (4 * k + 1 < LL) ? 4 * k + 1 : LL - 1;
        const int j2 = (4 * k + 2 < LL) ? 4 * k + 2 : LL - 1;
        const int j3 = (4 * k + 3 < LL) ? 4 * k + 3 : LL - 1;

        auto gstep = [&](fvec4 tc, hvec4 mo) {
            if (act) {
                hvec4 o;
                o[0] = (_Float16)fminf(m0, 60000.f);
                o[1] = (_Float16)fminf(m1, 60000.f);
                o[2] = (_Float16)fminf(m2, 60000.f);
                o[3] = (_Float16)fminf(m3, 60000.f);
                *(hvec4*)mst = o;
            }
            mst += mstr;
            float e0 = swap05 ? tc[3] : tc[0];
            float t0 = (e0    - (float)mo[0]) + m0;
            float t1 = (tc[1] - (float)mo[1]) + m1;
            float t2 = (tc[2] - (float)mo[2]) + m2;
            float t3 = (tc[3] - (float)mo[3]) + m3;
            __syncthreads();                 // prior reads done before rewrite
            if (okA) sht[g][4 * k] = t0;
            if (okB) {
                sht[g][4 * k + 1] = t1;
                sht[g][4 * k + 2] = t2;
                sht[g][4 * k + 3] = t3;
            }
            __syncthreads();
            float mnA = 1e30f, mnB = 1e30f, mnC = 1e30f, mnD = 1e30f;
            float gm  = 1e30f;
            for (int l = 0; l < LL; ++l) {
                float tl = sht[g][l];
                mnA = fminf(mnA, tl + shc[l * LL + j0]);
                mnB = fminf(mnB, tl + shc[l * LL + j1]);
                mnC = fminf(mnC, tl + shc[l * LL + j2]);
                mnD = fminf(mnD, tl + shc[l * LL + j3]);
                gm  = fminf(gm,  tl + shrm[l]);
            }
            m0 = mnA - gm; m1 = mnB - gm; m2 = mnC - gm; m3 = mnD - gm;
        };

        const int outer = (S - PD) / PD;
        for (int o = 0; o < outer; ++o) {
            #pragma unroll
            for (int i = 0; i < PD; ++i) {
                fvec4 tc = tf[i]; hvec4 mo = mf[i];
                tf[i] = load4u(tld);
                if (!FIRST) mf[i] = *(const hvec4*)mld;
                tld += tstr; mld += mstr;
                gstep(tc, mo);
            }
        }
        #pragma unroll
        for (int i = 0; i < PD; ++i) gstep(tf[i], mf[i]);
    }
}

// ---------------------------------------------------------------------------
extern "C" void kernel_launch(void* const* d_in, const int* in_sizes, int n_in,
                              void* d_out, int out_size, void* d_ws, size_t ws_size,
                              hipStream_t stream)
{
    (void)in_sizes; (void)n_in; (void)out_size; (void)ws_size;

    const float* phi = (const float*)d_in[0];
    const float* ctx = (const float*)d_in[1];   // [4,21,21]
    float*     out   = (float*)d_out;           // packed final output
    _Float16*  msgs  = (_Float16*)d_ws;         // 4 padded fp16 fields (96 MB)
    float*     totp  = (float*)((char*)d_ws + 4 * MFLD * sizeof(_Float16));
                                                // padded fp32 tot (48 MB)

    const int EW_BLOCKS = PIX / 256;            // 2048, exact
    const int SW_BLOCKS = 6144 / 8;             // 768 one-wave blocks

    // iteration 1: total == phi (packed), old msgs == 0 (never read)
    sweep_kernel<true><<<SW_BLOCKS, 64, 0, stream>>>(phi, ctx, msgs);

    for (int it = 1; it < 5; ++it) {
        ewise_kernel<<<EW_BLOCKS, 256, 0, stream>>>(phi, msgs, totp, 1.0f, 1);
        sweep_kernel<false><<<SW_BLOCKS, 64, 0, stream>>>(totp, ctx, msgs);
    }

    // final belief: phi*GAMMA_MNODE + sum of messages (packed to d_out)
    ewise_kernel<<<EW_BLOCKS, 256, 0, stream>>>(phi, msgs, out, 2.0f, 0);
}

// Round 8
// 551.237 us; speedup vs baseline: 1.7483x; 1.2376x over previous
//
#include <hip/hip_runtime.h>

// Problem constants (fixed by setup_inputs)
#define BB 4
#define HH 256
#define WW 512
#define LL 21
#define PIX (BB*HH*WW)            // 524288 pixels
#define MSL 24                    // uint8 labels per pixel (24 B rows)
#define TSL 24                    // fp16 labels per pixel  (48 B rows)
#define MFLD ((size_t)PIX*MSL)    // bytes per direction's msg field
#define PD 32                     // prefetch distance; divides 480 and 224

typedef float    fvec4 __attribute__((ext_vector_type(4)));
typedef _Float16 hvec4 __attribute__((ext_vector_type(4)));
typedef _Float16 hvec8 __attribute__((ext_vector_type(8)));

__device__ __forceinline__ fvec4 load4u(const float* p) {
    fvec4 v; __builtin_memcpy(&v, p, 16); return v;
}
__device__ __forceinline__ void store4u(float* p, fvec4 v) {
    __builtin_memcpy(p, &v, 16);
}

// ---------------------------------------------------------------------------
// pad: tot = phi, fp16 padded-24 (pads = 0). One pixel per thread.
// ---------------------------------------------------------------------------
__global__ __launch_bounds__(256) void pad_kernel(
    const float* __restrict__ phi, _Float16* __restrict__ tot)
{
    int p = blockIdx.x * 256 + threadIdx.x;      // < PIX
    const float* pp = phi + (size_t)p * LL;
    float r[24];
    fvec4 u0 = load4u(pp + 0), u1 = load4u(pp + 4), u2 = load4u(pp + 8);
    fvec4 u3 = load4u(pp + 12), u4 = load4u(pp + 16);
    #pragma unroll
    for (int e = 0; e < 4; ++e) {
        r[e] = u0[e]; r[4+e] = u1[e]; r[8+e] = u2[e];
        r[12+e] = u3[e]; r[16+e] = u4[e];
    }
    r[20] = pp[20];
    r[21] = r[22] = r[23] = 0.f;

    _Float16* op = tot + (size_t)p * TSL;
    #pragma unroll
    for (int c3 = 0; c3 < 3; ++c3) {
        hvec8 h;
        #pragma unroll
        for (int e = 0; e < 8; ++e) h[e] = (_Float16)r[8*c3 + e];
        *(hvec8*)(op + 8*c3) = h;
    }
}

// ---------------------------------------------------------------------------
// Elementwise: r = phi*scale + sum_d decode(msg_d).
// padded_out=1 -> fp16 padded-24 tot scratch; 0 -> packed-21 fp32 (d_out).
// ---------------------------------------------------------------------------
__global__ __launch_bounds__(256) void ewise_kernel(
    const float* __restrict__ phi, const unsigned char* __restrict__ msgs,
    const float* __restrict__ scales,
    float* __restrict__ outf, _Float16* __restrict__ outh,
    float scale, int padded_out)
{
    int p = blockIdx.x * 256 + threadIdx.x;      // < PIX
    const float* pp = phi + (size_t)p * LL;

    float r[24];
    {
        fvec4 u0 = load4u(pp + 0), u1 = load4u(pp + 4), u2 = load4u(pp + 8);
        fvec4 u3 = load4u(pp + 12), u4 = load4u(pp + 16);
        #pragma unroll
        for (int e = 0; e < 4; ++e) {
            r[e]      = u0[e] * scale;
            r[4 + e]  = u1[e] * scale;
            r[8 + e]  = u2[e] * scale;
            r[12 + e] = u3[e] * scale;
            r[16 + e] = u4[e] * scale;
        }
        r[20] = pp[20] * scale;
        r[21] = r[22] = r[23] = 0.f;
    }

    fvec4 sc = load4u(scales);                   // per-dir ranges R

    #pragma unroll
    for (int d = 0; d < 4; ++d) {
        const unsigned* mp =
            (const unsigned*)(msgs + (size_t)d * MFLD + (size_t)p * MSL);
        uint2 w0 = *(const uint2*)(mp + 0);      // rows are 8-B aligned
        uint2 w1 = *(const uint2*)(mp + 2);
        uint2 w2 = *(const uint2*)(mp + 4);
        unsigned w[6] = { w0.x, w0.y, w1.x, w1.y, w2.x, w2.y };
        float rs = sc[d] * (1.f / 255.f);
        #pragma unroll
        for (int j = 0; j < 21; ++j)
            r[j] += (float)((w[j >> 2] >> ((j & 3) * 8)) & 0xffu) * rs;
    }

    if (padded_out) {
        _Float16* op = outh + (size_t)p * TSL;
        r[21] = r[22] = r[23] = 0.f;
        #pragma unroll
        for (int c3 = 0; c3 < 3; ++c3) {
            hvec8 h;
            #pragma unroll
            for (int e = 0; e < 8; ++e) h[e] = (_Float16)r[8*c3 + e];
            *(hvec8*)(op + 8*c3) = h;
        }
    } else {
        float* op = outf + (size_t)p * LL;
        store4u(op + 0,  *(const fvec4*)(r + 0));
        store4u(op + 4,  *(const fvec4*)(r + 4));
        store4u(op + 8,  *(const fvec4*)(r + 8));
        store4u(op + 12, *(const fvec4*)(r + 12));
        store4u(op + 16, *(const fvec4*)(r + 16));
        op[20] = r[20];
    }
}

// ---------------------------------------------------------------------------
// 8-lane-group min/max (broadcast to all 8 lanes), pure DPP — no DS pipe.
// ---------------------------------------------------------------------------
__device__ __forceinline__ float min8(float x)
{
    int xi = __float_as_int(x); int y;
    y = __builtin_amdgcn_update_dpp(xi, xi, 0xB1, 0xf, 0xf, false);
    x = fminf(x, __int_as_float(y)); xi = __float_as_int(x);
    y = __builtin_amdgcn_update_dpp(xi, xi, 0x4E, 0xf, 0xf, false);
    x = fminf(x, __int_as_float(y)); xi = __float_as_int(x);
    y = __builtin_amdgcn_update_dpp(xi, xi, 0x141, 0xf, 0xf, false);
    x = fminf(x, __int_as_float(y));
    return x;
}
__device__ __forceinline__ float max8(float x)
{
    int xi = __float_as_int(x); int y;
    y = __builtin_amdgcn_update_dpp(xi, xi, 0xB1, 0xf, 0xf, false);
    x = fmaxf(x, __int_as_float(y)); xi = __float_as_int(x);
    y = __builtin_amdgcn_update_dpp(xi, xi, 0x4E, 0xf, 0xf, false);
    x = fmaxf(x, __int_as_float(y)); xi = __float_as_int(x);
    y = __builtin_amdgcn_update_dpp(xi, xi, 0x141, 0xf, 0xf, false);
    x = fmaxf(x, __int_as_float(y));
    return x;
}

// ---------------------------------------------------------------------------
// Directional sweep, all 4 directions in one launch (d is block-uniform).
// 8 lanes/scanline; lane k<6 owns labels {4k..4k+3}; lanes 6,7 dummy.
// tot: fp16 padded-24 (8 B/lane).  msgs: uint8 padded-24, q = m*255/R,
// R = max(ctx)-min(ctx) per dir (provably m in [0,R]; Potts: R = c).
// In-place msgs: position p read (prefetch) at step p-PD, written at p.
//
// Potts fast path (unnormalized, exact):
//   Tmin_s = min_l T_s(l);  Q_s = Tmin_s + c
//   T_{s+1}(l) = u_{s+1}(l) + min(T_s(l), Q_s)
//   m_{s+1}(l) = min(T_s(l), Q_s) - Tmin_s          (m_0 = 0)
// ---------------------------------------------------------------------------
template<bool FIRST>
__global__ __launch_bounds__(64) void sweep_kernel(
    const _Float16* __restrict__ tot, const float* __restrict__ ctx,
    unsigned char* __restrict__ msgs, float* __restrict__ scales)
{
    __shared__ float shc[LL * LL];   // general (non-Potts) path only
    __shared__ float shrm[LL];
    __shared__ float sht[8][MSL];

    const int lane = threadIdx.x;
    const int g = lane >> 3, k = lane & 7;
    const int line = blockIdx.x * 8 + g;

    int d, S, tstr, mstr;
    size_t pbase;
    if (line < 2048) {                    // horizontal
        d = line >> 10;                   // 0 or 1
        int r = line & 1023;              // b*H + h  (B*H = 1024)
        S = WW;
        pbase = (size_t)r * WW;
        tstr = TSL; mstr = MSL;
        if (d == 1) { pbase += WW - 1; tstr = -tstr; mstr = -mstr; }
    } else {                              // vertical
        int v = line - 2048;
        d = 2 + (v >> 11);                // 2 or 3
        int r = v & 2047;
        int bb = r >> 9, w = r & 511;
        S = HH;
        pbase = (size_t)bb * HH * WW + w;
        tstr = WW * TSL; mstr = WW * MSL;
        if (d == 3) { pbase += (size_t)(HH - 1) * WW; tstr = -tstr; mstr = -mstr; }
    }

    const float* ctxd = ctx + d * (LL * LL);
    const float  c    = ctxd[1];          // candidate Potts constant

    // Potts detection + ctx range (lane k scans its columns 4k..4k+3)
    bool bad = (c < 0.f);
    float cmx = -1e30f, cmn = 1e30f;
    #pragma unroll
    for (int e = 0; e < 4; ++e) {
        int j = 4 * k + e;
        if (j < LL) {
            for (int l = 0; l < LL; ++l) {
                float v = ctxd[l * LL + j];
                float want = (l == j) ? 0.f : c;
                if (v != want) bad = true;
                cmx = fmaxf(cmx, v); cmn = fminf(cmn, v);
            }
        }
    }
    const bool potts = (__ballot(bad) == 0ull);
    const float R    = fmaxf(max8(cmx) - min8(cmn), 0.f);
    const float s255 = (R > 0.f) ? 255.f / R : 0.f;
    const float rs   = R * (1.f / 255.f);

    if (FIRST && lane == 0) scales[d] = R;   // same value from every block

    const bool act = (k < 6);
    const bool okA = (k < 6);             // component 0 valid
    const bool okB = (k < 5);             // components 1..3 valid
    const int  koff = act ? 4 * k : 0;    // dummies alias lane-0 addresses

    const _Float16*      tp = tot + pbase * TSL + koff;
    unsigned char*       mb = msgs + (size_t)d * MFLD + pbase * MSL + koff;

    // register prefetch FIFO
    hvec4 tf[PD]; unsigned mf[PD];
    #pragma unroll
    for (int i = 0; i < PD; ++i) {
        tf[i] = *(const hvec4*)(tp + (ptrdiff_t)i * tstr);
        mf[i] = FIRST ? 0u : *(const unsigned*)(mb + (ptrdiff_t)i * mstr);
    }
    const _Float16* tld = tp + (ptrdiff_t)PD * tstr;
    const unsigned char* mld = mb + (ptrdiff_t)PD * mstr;
    unsigned char* mst = mb;

    if (potts) {
        float mn0 = 0.f, mn1 = 0.f, mn2 = 0.f, mn3 = 0.f, tminp = 0.f;

        auto step = [&](hvec4 th, unsigned w) {
            if (act) {
                float off = fmaf(-tminp, s255, 0.5f);
                unsigned q0 = (unsigned)fmaf(mn0, s255, off);
                unsigned q1 = (unsigned)fmaf(mn1, s255, off);
                unsigned q2 = (unsigned)fmaf(mn2, s255, off);
                unsigned q3 = (unsigned)fmaf(mn3, s255, off);
                *(unsigned*)mst = q0 | (q1 << 8) | (q2 << 16) | (q3 << 24);
            }
            mst += mstr;
            float T0, T1, T2, T3;
            if (FIRST) {
                T0 = (float)th[0] + mn0; T1 = (float)th[1] + mn1;
                T2 = (float)th[2] + mn2; T3 = (float)th[3] + mn3;
            } else {
                T0 = fmaf(-rs, (float)( w        & 0xffu), (float)th[0]) + mn0;
                T1 = fmaf(-rs, (float)((w >>  8) & 0xffu), (float)th[1]) + mn1;
                T2 = fmaf(-rs, (float)((w >> 16) & 0xffu), (float)th[2]) + mn2;
                T3 = fmaf(-rs, (float)( w >> 24        ), (float)th[3]) + mn3;
            }
            T0 = okA ? T0 : 1e30f;        // sanitize pads/dummies
            T1 = okB ? T1 : 1e30f;
            T2 = okB ? T2 : 1e30f;
            T3 = okB ? T3 : 1e30f;
            float lm = fminf(fminf(T0, T1), fminf(T2, T3));
            lm = min8(lm);
            float Q = lm + c;
            mn0 = fminf(T0, Q); mn1 = fminf(T1, Q);
            mn2 = fminf(T2, Q); mn3 = fminf(T3, Q);
            tminp = lm;
        };

        const int outer = (S - PD) / PD;
        for (int o = 0; o < outer; ++o) {
            #pragma unroll
            for (int i = 0; i < PD; ++i) {
                hvec4 th = tf[i]; unsigned w = mf[i];
                tf[i] = *(const hvec4*)tld;
                if (!FIRST) mf[i] = *(const unsigned*)mld;
                tld += tstr; mld += mstr;
                step(th, w);
            }
        }
        #pragma unroll
        for (int i = 0; i < PD; ++i) step(tf[i], mf[i]);
    } else {
        // -------- general min-plus path (correct for arbitrary ctx; not
        // taken on the bench input). ctx + rowmin staged in LDS. --------
        for (int i = lane; i < LL * LL; i += 64) shc[i] = ctxd[i];
        __syncthreads();
        if (lane < LL) {
            float mn = shc[lane * LL];
            for (int j = 1; j < LL; ++j) mn = fminf(mn, shc[lane * LL + j]);
            shrm[lane] = mn;
        }
        __syncthreads();

        float m0 = 0.f, m1 = 0.f, m2 = 0.f, m3 = 0.f;
        const int j0 = (4 * k     < LL) ? 4 * k     : LL - 1;
        const int j1 = (4 * k + 1 < LL) ? 4 * k + 1 : LL - 1;
        const int j2 = (4 * k + 2 < LL) ? 4 * k + 2 : LL - 1;
        const int j3 = (4 * k + 3 < LL) ? 4 * k + 3 : LL - 1;

        auto gstep = [&](hvec4 th, unsigned w) {
            if (act) {
                unsigned q0 = (unsigned)fminf(fmaf(m0, s255, 0.5f), 255.f);
                unsigned q1 = (unsigned)fminf(fmaf(m1, s255, 0.5f), 255.f);
                unsigned q2 = (unsigned)fminf(fmaf(m2, s255, 0.5f), 255.f);
                unsigned q3 = (unsigned)fminf(fmaf(m3, s255, 0.5f), 255.f);
                *(unsigned*)mst = q0 | (q1 << 8) | (q2 << 16) | (q3 << 24);
            }
            mst += mstr;
            float t0, t1, t2, t3;
            if (FIRST) {
                t0 = (float)th[0] + m0; t1 = (float)th[1] + m1;
                t2 = (float)th[2] + m2; t3 = (float)th[3] + m3;
            } else {
                t0 = fmaf(-rs, (float)( w        & 0xffu), (float)th[0]) + m0;
                t1 = fmaf(-rs, (float)((w >>  8) & 0xffu), (float)th[1]) + m1;
                t2 = fmaf(-rs, (float)((w >> 16) & 0xffu), (float)th[2]) + m2;
                t3 = fmaf(-rs, (float)( w >> 24        ), (float)th[3]) + m3;
            }
            __syncthreads();                 // prior reads done before rewrite
            if (okA) sht[g][4 * k] = t0;
            if (okB) {
                sht[g][4 * k + 1] = t1;
                sht[g][4 * k + 2] = t2;
                sht[g][4 * k + 3] = t3;
            }
            __syncthreads();
            float mnA = 1e30f, mnB = 1e30f, mnC = 1e30f, mnD = 1e30f;
            float gm  = 1e30f;
            for (int l = 0; l < LL; ++l) {
                float tl = sht[g][l];
                mnA = fminf(mnA, tl + shc[l * LL + j0]);
                mnB = fminf(mnB, tl + shc[l * LL + j1]);
                mnC = fminf(mnC, tl + shc[l * LL + j2]);
                mnD = fminf(mnD, tl + shc[l * LL + j3]);
                gm  = fminf(gm,  tl + shrm[l]);
            }
            m0 = mnA - gm; m1 = mnB - gm; m2 = mnC - gm; m3 = mnD - gm;
        };

        const int outer = (S - PD) / PD;
        for (int o = 0; o < outer; ++o) {
            #pragma unroll
            for (int i = 0; i < PD; ++i) {
                hvec4 th = tf[i]; unsigned w = mf[i];
                tf[i] = *(const hvec4*)tld;
                if (!FIRST) mf[i] = *(const unsigned*)mld;
                tld += tstr; mld += mstr;
                gstep(th, w);
            }
        }
        #pragma unroll
        for (int i = 0; i < PD; ++i) gstep(tf[i], mf[i]);
    }
}

// ---------------------------------------------------------------------------
extern "C" void kernel_launch(void* const* d_in, const int* in_sizes, int n_in,
                              void* d_out, int out_size, void* d_ws, size_t ws_size,
                              hipStream_t stream)
{
    (void)in_sizes; (void)n_in; (void)out_size; (void)ws_size;

    const float* phi = (const float*)d_in[0];
    const float* ctx = (const float*)d_in[1];   // [4,21,21]
    float* out = (float*)d_out;                 // packed final output

    unsigned char* msgs = (unsigned char*)d_ws;            // 4 uint8 fields (50.3 MB)
    _Float16* totp = (_Float16*)((char*)d_ws + 4 * MFLD);  // fp16 tot (25.2 MB)
    float* scales  = (float*)((char*)totp + (size_t)PIX * TSL * sizeof(_Float16));

    const int EW_BLOCKS = PIX / 256;            // 2048, exact
    const int SW_BLOCKS = 6144 / 8;             // 768 one-wave blocks

    // tot = phi (fp16 padded)
    pad_kernel<<<EW_BLOCKS, 256, 0, stream>>>(phi, totp);

    // iteration 1: old msgs == 0 (never read); writes scales[] for ewise
    sweep_kernel<true><<<SW_BLOCKS, 64, 0, stream>>>(totp, ctx, msgs, scales);

    for (int it = 1; it < 5; ++it) {
        ewise_kernel<<<EW_BLOCKS, 256, 0, stream>>>(phi, msgs, scales,
                                                    nullptr, totp, 1.0f, 1);
        sweep_kernel<false><<<SW_BLOCKS, 64, 0, stream>>>(totp, ctx, msgs, scales);
    }

    // final belief: phi*GAMMA_MNODE + sum of messages (packed fp32 to d_out)
    ewise_kernel<<<EW_BLOCKS, 256, 0, stream>>>(phi, msgs, scales,
                                                out, nullptr, 2.0f, 0);
}